// Round 1
// baseline (294.505 us; speedup 1.0000x reference)
//
#include <hip/hip_runtime.h>
#include <hip/hip_bf16.h>
#include <stdint.h>

#define NE 1024
#define NH 16
#define HD 64
#define BB 2
#define TT 2048
#define MM (BB*TT)

typedef __attribute__((ext_vector_type(8))) short short8;
typedef __attribute__((ext_vector_type(4))) float floatx4;

__device__ __forceinline__ short f2bf(float f) {
    union { float f; uint32_t u; } v; v.f = f;
    uint32_t u = v.u;
    return (short)((u + 0x7fffu + ((u >> 16) & 1u)) >> 16);
}

__device__ __forceinline__ void gload_lds16(const void* g, void* l) {
    __builtin_amdgcn_global_load_lds((__attribute__((address_space(1))) void*)g,
                                     (__attribute__((address_space(3))) void*)l,
                                     16, 0, 0);
}

// ---- fp32 -> bf16 elementwise, 8 elems/thread ----
__global__ void cvt_bf16(const float* __restrict__ in, short* __restrict__ out, int n8) {
    int i = blockIdx.x * blockDim.x + threadIdx.x;
    if (i >= n8) return;
    const floatx4* p = (const floatx4*)(in + (size_t)i * 8);
    floatx4 a = p[0], b = p[1];
    short8 r;
    #pragma unroll
    for (int j = 0; j < 4; j++) { r[j] = f2bf(a[j]); r[4 + j] = f2bf(b[j]); }
    *(short8*)(out + (size_t)i * 8) = r;
}

// ---- W [K,N] fp32 -> Wt [N,K] bf16 (transpose + convert) ----
__global__ void wtrans(const float* __restrict__ Wq, const float* __restrict__ Wk,
                       const float* __restrict__ Wv, short* __restrict__ Wt) {
    __shared__ float t[32][33];
    const float* W = blockIdx.z == 0 ? Wq : (blockIdx.z == 1 ? Wk : Wv);
    short* dst = Wt + (size_t)blockIdx.z * NE * NE;
    int n0 = blockIdx.x * 32, k0 = blockIdx.y * 32;
    int tx = threadIdx.x & 31, ty = threadIdx.x >> 5;
    #pragma unroll
    for (int i = 0; i < 4; i++)
        t[ty * 4 + i][tx] = W[(size_t)(k0 + ty * 4 + i) * NE + n0 + tx];
    __syncthreads();
    #pragma unroll
    for (int i = 0; i < 4; i++)
        dst[(size_t)(n0 + ty * 4 + i) * NE + k0 + tx] = f2bf(t[tx][ty * 4 + i]);
}

// ---- GEMM: C[M,N] bf16 = A[M,K] bf16 @ Bt[N,K]^T ; M=4096, N=K=1024 ----
// z: 0=q (x@Wq), 1=k (x_enc@Wk), 2=v (x_enc@Wv). 128x128 tile, BK=32, 4 waves.
__global__ void __launch_bounds__(256) gemm_bt(const short* __restrict__ x_bf,
                                               const short* __restrict__ xenc_bf,
                                               const short* __restrict__ Wt,
                                               short* __restrict__ qkv) {
    __shared__ short sA[128 * 32];
    __shared__ short sB[128 * 32];
    const int z = blockIdx.z;
    const short* A  = (z == 0) ? x_bf : xenc_bf;
    const short* Bt = Wt + (size_t)z * NE * NE;
    short* C = qkv + (size_t)z * MM * NE;

    const int tid = threadIdx.x;
    const int lane = tid & 63, wid = tid >> 6;
    const int l15 = lane & 15, lg = lane >> 4;
    const int wr = wid >> 1, wc = wid & 1;
    const int m0 = blockIdx.y * 128, n0 = blockIdx.x * 128;

    const short* gA = A  + (size_t)(m0 + (tid >> 2)) * NE + (tid & 3) * 8;
    const short* gB = Bt + (size_t)(n0 + (tid >> 2)) * NE + (tid & 3) * 8;
    short* lA = sA + wid * 512;   // wave-uniform LDS base (lane i -> +i*16B)
    short* lB = sB + wid * 512;

    floatx4 acc[4][4];
    floatx4 zero = {0.f, 0.f, 0.f, 0.f};
    #pragma unroll
    for (int i = 0; i < 4; i++)
        #pragma unroll
        for (int j = 0; j < 4; j++) acc[i][j] = zero;

    for (int kt = 0; kt < NE; kt += 32) {
        gload_lds16(gA + kt,            lA);
        gload_lds16(gA + 64 * NE + kt,  lA + 2048);
        gload_lds16(gB + kt,            lB);
        gload_lds16(gB + 64 * NE + kt,  lB + 2048);
        __syncthreads();
        short8 af[4], bfr[4];
        #pragma unroll
        for (int i = 0; i < 4; i++) {
            af[i]  = *(const short8*)&sA[(wr * 64 + i * 16 + l15) * 32 + lg * 8];
            bfr[i] = *(const short8*)&sB[(wc * 64 + i * 16 + l15) * 32 + lg * 8];
        }
        #pragma unroll
        for (int i = 0; i < 4; i++)
            #pragma unroll
            for (int j = 0; j < 4; j++)
                acc[i][j] = __builtin_amdgcn_mfma_f32_16x16x32_bf16(af[i], bfr[j], acc[i][j], 0, 0, 0);
        __syncthreads();
    }
    #pragma unroll
    for (int i = 0; i < 4; i++)
        #pragma unroll
        for (int j = 0; j < 4; j++)
            #pragma unroll
            for (int r = 0; r < 4; r++) {
                int row = m0 + wr * 64 + i * 16 + lg * 4 + r;
                int col = n0 + wc * 64 + j * 16 + l15;
                C[(size_t)row * NE + col] = f2bf(acc[i][j][r]);
            }
}

// ---- v [B*T, NE] bf16 -> vt [(b*16+h)*64+d][s] bf16 ----
__global__ void vtrans(const short* __restrict__ v, short* __restrict__ vt) {
    __shared__ short t[64][65];
    int s0 = blockIdx.x * 64;
    int bh = blockIdx.y;
    int b = bh >> 4, h = bh & 15;
    int tid = threadIdx.x;
    int c = tid & 63, rr = tid >> 6;
    #pragma unroll
    for (int i = 0; i < 16; i++)
        t[i * 4 + rr][c] = v[(size_t)(b * TT + s0 + i * 4 + rr) * NE + h * HD + c];
    __syncthreads();
    #pragma unroll
    for (int i = 0; i < 16; i++)
        vt[(size_t)(bh * HD + i * 4 + rr) * TT + s0 + c] = t[c][i * 4 + rr];
}

// ---- flash attention: 4 waves x 16 q-rows, KV tile = 64, K/V from global (L2-resident) ----
__global__ void __launch_bounds__(256) fattn(const short* __restrict__ q,
                                             const short* __restrict__ k,
                                             const short* __restrict__ vt,
                                             float* __restrict__ out) {
    __shared__ float plds[4][16][68];
    const int tid = threadIdx.x, lane = tid & 63, wid = tid >> 6;
    const int l15 = lane & 15, lg = lane >> 4;
    const int q0 = blockIdx.x * 64 + wid * 16;
    const int bh = blockIdx.y, b = bh >> 4, h = bh & 15;

    const short* qbase = q + (size_t)(b * TT + q0 + l15) * NE + h * HD;
    short8 aq0 = *(const short8*)(qbase + lg * 8);
    short8 aq1 = *(const short8*)(qbase + 32 + lg * 8);

    floatx4 acc_o[4];
    float m_run[4], l_run[4];
    floatx4 zero = {0.f, 0.f, 0.f, 0.f};
    #pragma unroll
    for (int r = 0; r < 4; r++) { acc_o[r] = zero; m_run[r] = -1e30f; l_run[r] = 0.f; }
    const float scl = 0.03125f * 1.44269504088896340736f;  // (1/sqrt(1024))*log2(e)

    const short* kbase = k + (size_t)(b * TT) * NE + h * HD;
    const short* vbase = vt + (size_t)(bh * HD) * TT;
    float (*P)[68] = plds[wid];

    for (int s0 = 0; s0 < TT; s0 += 64) {
        floatx4 accs[4];
        #pragma unroll
        for (int cb = 0; cb < 4; cb++) accs[cb] = zero;
        #pragma unroll
        for (int cb = 0; cb < 4; cb++) {
            const short* kr = kbase + (size_t)(s0 + cb * 16 + l15) * NE;
            short8 b0 = *(const short8*)(kr + lg * 8);
            short8 b1 = *(const short8*)(kr + 32 + lg * 8);
            accs[cb] = __builtin_amdgcn_mfma_f32_16x16x32_bf16(aq0, b0, accs[cb], 0, 0, 0);
            accs[cb] = __builtin_amdgcn_mfma_f32_16x16x32_bf16(aq1, b1, accs[cb], 0, 0, 0);
        }
        // online softmax per q-row (row = lg*4+r, cols spread over 16 lanes x 4 blocks)
        #pragma unroll
        for (int r = 0; r < 4; r++) {
            float v0 = accs[0][r] * scl, v1 = accs[1][r] * scl;
            float v2 = accs[2][r] * scl, v3 = accs[3][r] * scl;
            float pm = fmaxf(fmaxf(v0, v1), fmaxf(v2, v3));
            pm = fmaxf(pm, __shfl_xor(pm, 1));
            pm = fmaxf(pm, __shfl_xor(pm, 2));
            pm = fmaxf(pm, __shfl_xor(pm, 4));
            pm = fmaxf(pm, __shfl_xor(pm, 8));
            float mn = fmaxf(m_run[r], pm);
            float alpha = exp2f(m_run[r] - mn);
            m_run[r] = mn;
            float p0 = exp2f(v0 - mn), p1 = exp2f(v1 - mn);
            float p2 = exp2f(v2 - mn), p3 = exp2f(v3 - mn);
            float rs = p0 + p1 + p2 + p3;
            rs += __shfl_xor(rs, 1); rs += __shfl_xor(rs, 2);
            rs += __shfl_xor(rs, 4); rs += __shfl_xor(rs, 8);
            l_run[r] = l_run[r] * alpha + rs;
            #pragma unroll
            for (int db = 0; db < 4; db++) acc_o[db][r] *= alpha;
            int row = lg * 4 + r;
            P[row][l15] = p0; P[row][16 + l15] = p1;
            P[row][32 + l15] = p2; P[row][48 + l15] = p3;
        }
        __syncthreads();
        // PV: A = P (reload in A-layout from LDS, cvt to bf16), B = Vt rows (contig s)
        #pragma unroll
        for (int ks = 0; ks < 2; ks++) {
            floatx4 pA = *(const floatx4*)&P[l15][ks * 32 + lg * 8];
            floatx4 pB = *(const floatx4*)&P[l15][ks * 32 + lg * 8 + 4];
            short8 pa;
            #pragma unroll
            for (int j = 0; j < 4; j++) { pa[j] = f2bf(pA[j]); pa[4 + j] = f2bf(pB[j]); }
            #pragma unroll
            for (int db = 0; db < 4; db++) {
                const short* vr = vbase + (size_t)(db * 16 + l15) * TT + s0 + ks * 32 + lg * 8;
                short8 bv = *(const short8*)vr;
                acc_o[db] = __builtin_amdgcn_mfma_f32_16x16x32_bf16(pa, bv, acc_o[db], 0, 0, 0);
            }
        }
        __syncthreads();
    }
    #pragma unroll
    for (int r = 0; r < 4; r++) {
        float inv = 1.0f / l_run[r];
        int row = q0 + lg * 4 + r;
        #pragma unroll
        for (int db = 0; db < 4; db++)
            out[(size_t)(b * TT + row) * NE + h * HD + db * 16 + l15] = acc_o[db][r] * inv;
    }
}

extern "C" void kernel_launch(void* const* d_in, const int* in_sizes, int n_in,
                              void* d_out, int out_size, void* d_ws, size_t ws_size,
                              hipStream_t stream) {
    const float* x_enc = (const float*)d_in[0];
    const float* x     = (const float*)d_in[1];
    const float* Wk    = (const float*)d_in[2];
    const float* Wq    = (const float*)d_in[3];
    const float* Wv    = (const float*)d_in[4];
    float* out = (float*)d_out;

    const size_t SZ = (size_t)MM * NE;      // 4,194,304 elems
    short* x_bf    = (short*)d_ws;          // SZ
    short* xenc_bf = x_bf + SZ;             // SZ
    short* Wt      = xenc_bf + SZ;          // 3*NE*NE (order: Wq, Wk, Wv)
    short* qkv     = Wt + 3 * (size_t)NE * NE;  // 3*SZ (order: q, k, v)
    short* vt      = qkv + 3 * SZ;          // SZ
    // total ws use: ~56.6 MB

    cvt_bf16<<<dim3(2048), dim3(256), 0, stream>>>(x,     x_bf,    (int)(SZ / 8));
    cvt_bf16<<<dim3(2048), dim3(256), 0, stream>>>(x_enc, xenc_bf, (int)(SZ / 8));
    wtrans<<<dim3(32, 32, 3), dim3(256), 0, stream>>>(Wq, Wk, Wv, Wt);
    gemm_bt<<<dim3(8, 32, 3), dim3(256), 0, stream>>>(x_bf, xenc_bf, Wt, qkv);
    vtrans<<<dim3(32, 32), dim3(256), 0, stream>>>(qkv + 2 * SZ, vt);
    fattn<<<dim3(32, 32), dim3(256), 0, stream>>>(qkv, qkv + SZ, vt, out);
}

// Round 2
// 175.837 us; speedup vs baseline: 1.6749x; 1.6749x over previous
//
#include <hip/hip_runtime.h>
#include <hip/hip_bf16.h>
#include <stdint.h>

#define NE 1024
#define NH 16
#define HD 64
#define BB 2
#define TT 2048
#define MM (BB*TT)

typedef __attribute__((ext_vector_type(8))) short short8;
typedef __attribute__((ext_vector_type(4))) float floatx4;

__device__ __forceinline__ short f2bf(float f) {
    union { float f; uint32_t u; } v; v.f = f;
    uint32_t u = v.u;
    return (short)((u + 0x7fffu + ((u >> 16) & 1u)) >> 16);
}

// HW-converted bf16 (compiler fuses pairs into v_cvt_pk_bf16_f32)
__device__ __forceinline__ short f2bf_hw(float f) {
    __hip_bfloat16 h = __float2bfloat16(f);
    union { __hip_bfloat16 h; short s; } u; u.h = h;
    return u.s;
}

__device__ __forceinline__ void gload_lds16(const void* g, void* l) {
    __builtin_amdgcn_global_load_lds((__attribute__((address_space(1))) void*)g,
                                     (__attribute__((address_space(3))) void*)l,
                                     16, 0, 0);
}

// ---- fp32 -> bf16 elementwise, 8 elems/thread ----
__global__ void cvt_bf16(const float* __restrict__ in, short* __restrict__ out, int n8) {
    int i = blockIdx.x * blockDim.x + threadIdx.x;
    if (i >= n8) return;
    const floatx4* p = (const floatx4*)(in + (size_t)i * 8);
    floatx4 a = p[0], b = p[1];
    short8 r;
    #pragma unroll
    for (int j = 0; j < 4; j++) { r[j] = f2bf(a[j]); r[4 + j] = f2bf(b[j]); }
    *(short8*)(out + (size_t)i * 8) = r;
}

// ---- W [K,N] fp32 -> Wt [N,K] bf16 (transpose + convert) ----
__global__ void wtrans(const float* __restrict__ Wq, const float* __restrict__ Wk,
                       const float* __restrict__ Wv, short* __restrict__ Wt) {
    __shared__ float t[32][33];
    const float* W = blockIdx.z == 0 ? Wq : (blockIdx.z == 1 ? Wk : Wv);
    short* dst = Wt + (size_t)blockIdx.z * NE * NE;
    int n0 = blockIdx.x * 32, k0 = blockIdx.y * 32;
    int tx = threadIdx.x & 31, ty = threadIdx.x >> 5;
    #pragma unroll
    for (int i = 0; i < 4; i++)
        t[ty * 4 + i][tx] = W[(size_t)(k0 + ty * 4 + i) * NE + n0 + tx];
    __syncthreads();
    #pragma unroll
    for (int i = 0; i < 4; i++)
        dst[(size_t)(n0 + ty * 4 + i) * NE + k0 + tx] = f2bf(t[tx][ty * 4 + i]);
}

// ---- GEMM: C[M,N] bf16 = A[M,K] bf16 @ Bt[N,K]^T ; M=4096, N=K=1024 ----
// z: 0=q (x@Wq, scaled by (1/sqrt(NE))*log2(e)), 1=k, 2=v. 128x128 tile, BK=32.
__global__ void __launch_bounds__(256) gemm_bt(const short* __restrict__ x_bf,
                                               const short* __restrict__ xenc_bf,
                                               const short* __restrict__ Wt,
                                               short* __restrict__ qkv) {
    __shared__ short sA[128 * 32];
    __shared__ short sB[128 * 32];
    const int z = blockIdx.z;
    const short* A  = (z == 0) ? x_bf : xenc_bf;
    const short* Bt = Wt + (size_t)z * NE * NE;
    short* C = qkv + (size_t)z * MM * NE;
    const float osc = (z == 0) ? 0.04508422f : 1.0f;  // (1/32)*log2(e)

    const int tid = threadIdx.x;
    const int lane = tid & 63, wid = tid >> 6;
    const int l15 = lane & 15, lg = lane >> 4;
    const int wr = wid >> 1, wc = wid & 1;
    const int m0 = blockIdx.y * 128, n0 = blockIdx.x * 128;

    const short* gA = A  + (size_t)(m0 + (tid >> 2)) * NE + (tid & 3) * 8;
    const short* gB = Bt + (size_t)(n0 + (tid >> 2)) * NE + (tid & 3) * 8;
    short* lA = sA + wid * 512;
    short* lB = sB + wid * 512;

    floatx4 acc[4][4];
    floatx4 zero = {0.f, 0.f, 0.f, 0.f};
    #pragma unroll
    for (int i = 0; i < 4; i++)
        #pragma unroll
        for (int j = 0; j < 4; j++) acc[i][j] = zero;

    for (int kt = 0; kt < NE; kt += 32) {
        gload_lds16(gA + kt,            lA);
        gload_lds16(gA + 64 * NE + kt,  lA + 2048);
        gload_lds16(gB + kt,            lB);
        gload_lds16(gB + 64 * NE + kt,  lB + 2048);
        __syncthreads();
        short8 af[4], bfr[4];
        #pragma unroll
        for (int i = 0; i < 4; i++) {
            af[i]  = *(const short8*)&sA[(wr * 64 + i * 16 + l15) * 32 + lg * 8];
            bfr[i] = *(const short8*)&sB[(wc * 64 + i * 16 + l15) * 32 + lg * 8];
        }
        #pragma unroll
        for (int i = 0; i < 4; i++)
            #pragma unroll
            for (int j = 0; j < 4; j++)
                acc[i][j] = __builtin_amdgcn_mfma_f32_16x16x32_bf16(af[i], bfr[j], acc[i][j], 0, 0, 0);
        __syncthreads();
    }
    #pragma unroll
    for (int i = 0; i < 4; i++)
        #pragma unroll
        for (int j = 0; j < 4; j++)
            #pragma unroll
            for (int r = 0; r < 4; r++) {
                int row = m0 + wr * 64 + i * 16 + lg * 4 + r;
                int col = n0 + wc * 64 + j * 16 + l15;
                C[(size_t)row * NE + col] = f2bf(acc[i][j][r] * osc);
            }
}

// ---- v [B*T, NE] bf16 -> vt[(bh)*64+d][s'] bf16, s' swizzled within 32-blocks
// so PV B-fragments are single 16B loads: pos(5b) bits s'4:3=s3:2, s'2=s4, s'1:0=s1:0
__global__ void vtrans(const short* __restrict__ v, short* __restrict__ vt) {
    __shared__ short t[64][65];
    int s0 = blockIdx.x * 64;
    int bh = blockIdx.y;
    int b = bh >> 4, h = bh & 15;
    int tid = threadIdx.x;
    int c = tid & 63, rr = tid >> 6;
    #pragma unroll
    for (int i = 0; i < 16; i++)
        t[i * 4 + rr][c] = v[(size_t)(b * TT + s0 + i * 4 + rr) * NE + h * HD + c];
    __syncthreads();
    int csw = (c & 35) | (((c >> 4) & 1) << 2) | (((c >> 2) & 3) << 3);
    #pragma unroll
    for (int i = 0; i < 16; i++)
        vt[(size_t)(bh * HD + i * 4 + rr) * TT + s0 + csw] = t[c][i * 4 + rr];
}

// ---- flash attention: swapped QK^T, in-register softmax, zero-shuffle P->PV ----
// 4 waves x 32 q-rows, KV tile 64, no LDS, no barriers. K/V direct from L1/L2.
__global__ void __launch_bounds__(256, 2) fattn(const short* __restrict__ q,
                                                const short* __restrict__ k,
                                                const short* __restrict__ vt,
                                                float* __restrict__ out) {
    const int tid = threadIdx.x, lane = tid & 63, wid = tid >> 6;
    const int l15 = lane & 15, lg = lane >> 4;
    const int q0 = blockIdx.x * 128 + wid * 32;
    const int bh = blockIdx.y, b = bh >> 4, h = bh & 15;

    // Q fragments [qb][dhalf]: B-operand, col=q(l15), k=d(lg*8+j)
    short8 qf[2][2];
    #pragma unroll
    for (int qb = 0; qb < 2; qb++) {
        const short* qp = q + (size_t)(b * TT + q0 + qb * 16 + l15) * NE + h * HD + lg * 8;
        qf[qb][0] = *(const short8*)qp;
        qf[qb][1] = *(const short8*)(qp + 32);
    }

    floatx4 acc_o[2][4];   // [qb][db], D row=q_local(4lg+r), col=d(16db+l15)
    float m_run[2] = {-1e30f, -1e30f}, l_run[2] = {0.f, 0.f};
    floatx4 zero = {0.f, 0.f, 0.f, 0.f};
    #pragma unroll
    for (int qb = 0; qb < 2; qb++)
        #pragma unroll
        for (int db = 0; db < 4; db++) acc_o[qb][db] = zero;

    const short* kbase = k + (size_t)(b * TT) * NE + h * HD;
    const short* vbase = vt + (size_t)(bh * HD) * TT;

    for (int s0 = 0; s0 < TT; s0 += 64) {
        // K fragments [cb][dhalf]: A-operand, row=k(16cb+l15), k=d
        short8 kf[4][2];
        #pragma unroll
        for (int cb = 0; cb < 4; cb++) {
            const short* kp = kbase + (size_t)(s0 + cb * 16 + l15) * NE + lg * 8;
            kf[cb][0] = *(const short8*)kp;
            kf[cb][1] = *(const short8*)(kp + 32);
        }
        // swapped QK^T: sacc[qb][cb] = P_log2[s=16cb+4lg+r][q=16qb+l15]
        floatx4 sacc[2][4];
        #pragma unroll
        for (int qb = 0; qb < 2; qb++)
            #pragma unroll
            for (int cb = 0; cb < 4; cb++) sacc[qb][cb] = zero;
        #pragma unroll
        for (int qb = 0; qb < 2; qb++)
            #pragma unroll
            for (int cb = 0; cb < 4; cb++) {
                sacc[qb][cb] = __builtin_amdgcn_mfma_f32_16x16x32_bf16(kf[cb][0], qf[qb][0], sacc[qb][cb], 0, 0, 0);
                sacc[qb][cb] = __builtin_amdgcn_mfma_f32_16x16x32_bf16(kf[cb][1], qf[qb][1], sacc[qb][cb], 0, 0, 0);
            }
        // V fragments [ks][db] from swizzled vt: one 16B load each (issued early)
        short8 vf[2][4];
        #pragma unroll
        for (int ks = 0; ks < 2; ks++)
            #pragma unroll
            for (int db = 0; db < 4; db++)
                vf[ks][db] = *(const short8*)(vbase + (size_t)(db * 16 + l15) * TT + s0 + ks * 32 + lg * 8);

        // in-register online softmax: lane owns q-row l15's 16 logits (x4 lg groups)
        short8 paf[2][2];
        float alpha[2];
        #pragma unroll
        for (int qb = 0; qb < 2; qb++) {
            float p[16];
            float mx = -1e30f;
            #pragma unroll
            for (int cb = 0; cb < 4; cb++)
                #pragma unroll
                for (int r = 0; r < 4; r++) {
                    p[cb * 4 + r] = sacc[qb][cb][r];
                    mx = fmaxf(mx, p[cb * 4 + r]);
                }
            mx = fmaxf(mx, __shfl_xor(mx, 16));
            mx = fmaxf(mx, __shfl_xor(mx, 32));
            float mn = fmaxf(m_run[qb], mx);
            alpha[qb] = exp2f(m_run[qb] - mn);
            m_run[qb] = mn;
            float rs = 0.f;
            #pragma unroll
            for (int i = 0; i < 16; i++) { p[i] = exp2f(p[i] - mn); rs += p[i]; }
            rs += __shfl_xor(rs, 16);
            rs += __shfl_xor(rs, 32);
            l_run[qb] = l_run[qb] * alpha[qb] + rs;
            // pack: A-frag[ks] element j = p[8ks+j]  (s_map matches vt swizzle)
            #pragma unroll
            for (int ks = 0; ks < 2; ks++) {
                short8 pa;
                #pragma unroll
                for (int j = 0; j < 8; j++) pa[j] = f2bf_hw(p[ks * 8 + j]);
                paf[qb][ks] = pa;
            }
        }
        // rescale acc_o by alpha (broadcast from QK layout lane 4lg+r)
        #pragma unroll
        for (int qb = 0; qb < 2; qb++) {
            #pragma unroll
            for (int r = 0; r < 4; r++) {
                float al = __shfl(alpha[qb], lg * 4 + r);
                #pragma unroll
                for (int db = 0; db < 4; db++) acc_o[qb][db][r] *= al;
            }
        }
        // PV
        #pragma unroll
        for (int qb = 0; qb < 2; qb++)
            #pragma unroll
            for (int ks = 0; ks < 2; ks++)
                #pragma unroll
                for (int db = 0; db < 4; db++)
                    acc_o[qb][db] = __builtin_amdgcn_mfma_f32_16x16x32_bf16(paf[qb][ks], vf[ks][db], acc_o[qb][db], 0, 0, 0);
    }
    // epilogue: normalize by l (broadcast from QK layout) and store fp32
    #pragma unroll
    for (int qb = 0; qb < 2; qb++) {
        #pragma unroll
        for (int r = 0; r < 4; r++) {
            float li = __shfl(l_run[qb], lg * 4 + r);
            float inv = 1.0f / li;
            #pragma unroll
            for (int db = 0; db < 4; db++)
                out[(size_t)(b * TT + q0 + qb * 16 + lg * 4 + r) * NE + h * HD + db * 16 + l15] =
                    acc_o[qb][db][r] * inv;
        }
    }
}

extern "C" void kernel_launch(void* const* d_in, const int* in_sizes, int n_in,
                              void* d_out, int out_size, void* d_ws, size_t ws_size,
                              hipStream_t stream) {
    const float* x_enc = (const float*)d_in[0];
    const float* x     = (const float*)d_in[1];
    const float* Wk    = (const float*)d_in[2];
    const float* Wq    = (const float*)d_in[3];
    const float* Wv    = (const float*)d_in[4];
    float* out = (float*)d_out;

    const size_t SZ = (size_t)MM * NE;
    short* x_bf    = (short*)d_ws;
    short* xenc_bf = x_bf + SZ;
    short* Wt      = xenc_bf + SZ;
    short* qkv     = Wt + 3 * (size_t)NE * NE;
    short* vt      = qkv + 3 * SZ;

    cvt_bf16<<<dim3(2048), dim3(256), 0, stream>>>(x,     x_bf,    (int)(SZ / 8));
    cvt_bf16<<<dim3(2048), dim3(256), 0, stream>>>(x_enc, xenc_bf, (int)(SZ / 8));
    wtrans<<<dim3(32, 32, 3), dim3(256), 0, stream>>>(Wq, Wk, Wv, Wt);
    gemm_bt<<<dim3(8, 32, 3), dim3(256), 0, stream>>>(x_bf, xenc_bf, Wt, qkv);
    vtrans<<<dim3(32, 32), dim3(256), 0, stream>>>(qkv + 2 * SZ, vt);
    fattn<<<dim3(16, 32), dim3(256), 0, stream>>>(qkv, qkv + SZ, vt, out);
}

// Round 3
// 136.739 us; speedup vs baseline: 2.1538x; 1.2859x over previous
//
#include <hip/hip_runtime.h>
#include <hip/hip_bf16.h>
#include <stdint.h>

#define NE 1024
#define NH 16
#define HD 64
#define BB 2
#define TT 2048
#define MM (BB*TT)

typedef __attribute__((ext_vector_type(8))) short short8;
typedef __attribute__((ext_vector_type(4))) float floatx4;

__device__ __forceinline__ short f2bf(float f) {
    union { float f; uint32_t u; } v; v.f = f;
    uint32_t u = v.u;
    return (short)((u + 0x7fffu + ((u >> 16) & 1u)) >> 16);
}

__device__ __forceinline__ short f2bf_hw(float f) {
    __hip_bfloat16 h = __float2bfloat16(f);
    union { __hip_bfloat16 h; short s; } u; u.h = h;
    return u.s;
}

__device__ __forceinline__ void gload_lds16(const void* g, void* l) {
    __builtin_amdgcn_global_load_lds((__attribute__((address_space(1))) void*)g,
                                     (__attribute__((address_space(3))) void*)l,
                                     16, 0, 0);
}

// ---- fp32 -> bf16 elementwise, 8 elems/thread ----
__global__ void cvt_bf16(const float* __restrict__ in, short* __restrict__ out, int n8) {
    int i = blockIdx.x * blockDim.x + threadIdx.x;
    if (i >= n8) return;
    const floatx4* p = (const floatx4*)(in + (size_t)i * 8);
    floatx4 a = p[0], b = p[1];
    short8 r;
    #pragma unroll
    for (int j = 0; j < 4; j++) { r[j] = f2bf(a[j]); r[4 + j] = f2bf(b[j]); }
    *(short8*)(out + (size_t)i * 8) = r;
}

// ---- W [K,N] fp32 -> Wt [N,K] bf16 (transpose + convert) ----
__global__ void wtrans(const float* __restrict__ Wq, const float* __restrict__ Wk,
                       const float* __restrict__ Wv, short* __restrict__ Wt) {
    __shared__ float t[32][33];
    const float* W = blockIdx.z == 0 ? Wq : (blockIdx.z == 1 ? Wk : Wv);
    short* dst = Wt + (size_t)blockIdx.z * NE * NE;
    int n0 = blockIdx.x * 32, k0 = blockIdx.y * 32;
    int tx = threadIdx.x & 31, ty = threadIdx.x >> 5;
    #pragma unroll
    for (int i = 0; i < 4; i++)
        t[ty * 4 + i][tx] = W[(size_t)(k0 + ty * 4 + i) * NE + n0 + tx];
    __syncthreads();
    #pragma unroll
    for (int i = 0; i < 4; i++)
        dst[(size_t)(n0 + ty * 4 + i) * NE + k0 + tx] = f2bf(t[tx][ty * 4 + i]);
}

// ---- GEMM: C[M,N] bf16 = A[M,K] bf16 @ Bt[N,K]^T ; M=4096, N=K=1024 ----
__global__ void __launch_bounds__(256) gemm_bt(const short* __restrict__ x_bf,
                                               const short* __restrict__ xenc_bf,
                                               const short* __restrict__ Wt,
                                               short* __restrict__ qkv) {
    __shared__ short sA[128 * 32];
    __shared__ short sB[128 * 32];
    const int z = blockIdx.z;
    const short* A  = (z == 0) ? x_bf : xenc_bf;
    const short* Bt = Wt + (size_t)z * NE * NE;
    short* C = qkv + (size_t)z * MM * NE;
    const float osc = (z == 0) ? 0.04508422f : 1.0f;  // (1/32)*log2(e)

    const int tid = threadIdx.x;
    const int lane = tid & 63, wid = tid >> 6;
    const int l15 = lane & 15, lg = lane >> 4;
    const int wr = wid >> 1, wc = wid & 1;
    const int m0 = blockIdx.y * 128, n0 = blockIdx.x * 128;

    const short* gA = A  + (size_t)(m0 + (tid >> 2)) * NE + (tid & 3) * 8;
    const short* gB = Bt + (size_t)(n0 + (tid >> 2)) * NE + (tid & 3) * 8;
    short* lA = sA + wid * 512;
    short* lB = sB + wid * 512;

    floatx4 acc[4][4];
    floatx4 zero = {0.f, 0.f, 0.f, 0.f};
    #pragma unroll
    for (int i = 0; i < 4; i++)
        #pragma unroll
        for (int j = 0; j < 4; j++) acc[i][j] = zero;

    for (int kt = 0; kt < NE; kt += 32) {
        gload_lds16(gA + kt,            lA);
        gload_lds16(gA + 64 * NE + kt,  lA + 2048);
        gload_lds16(gB + kt,            lB);
        gload_lds16(gB + 64 * NE + kt,  lB + 2048);
        __syncthreads();
        short8 af[4], bfr[4];
        #pragma unroll
        for (int i = 0; i < 4; i++) {
            af[i]  = *(const short8*)&sA[(wr * 64 + i * 16 + l15) * 32 + lg * 8];
            bfr[i] = *(const short8*)&sB[(wc * 64 + i * 16 + l15) * 32 + lg * 8];
        }
        #pragma unroll
        for (int i = 0; i < 4; i++)
            #pragma unroll
            for (int j = 0; j < 4; j++)
                acc[i][j] = __builtin_amdgcn_mfma_f32_16x16x32_bf16(af[i], bfr[j], acc[i][j], 0, 0, 0);
        __syncthreads();
    }
    #pragma unroll
    for (int i = 0; i < 4; i++)
        #pragma unroll
        for (int j = 0; j < 4; j++)
            #pragma unroll
            for (int r = 0; r < 4; r++) {
                int row = m0 + wr * 64 + i * 16 + lg * 4 + r;
                int col = n0 + wc * 64 + j * 16 + l15;
                C[(size_t)row * NE + col] = f2bf(acc[i][j][r] * osc);
            }
}

// ---- v [B*T, NE] bf16 -> vt[(bh)*64+d][s'] bf16, s' swizzled within 64-blocks ----
__global__ void vtrans(const short* __restrict__ v, short* __restrict__ vt) {
    __shared__ short t[64][65];
    int s0 = blockIdx.x * 64;
    int bh = blockIdx.y;
    int b = bh >> 4, h = bh & 15;
    int tid = threadIdx.x;
    int c = tid & 63, rr = tid >> 6;
    #pragma unroll
    for (int i = 0; i < 16; i++)
        t[i * 4 + rr][c] = v[(size_t)(b * TT + s0 + i * 4 + rr) * NE + h * HD + c];
    __syncthreads();
    int csw = (c & 35) | (((c >> 4) & 1) << 2) | (((c >> 2) & 3) << 3);
    #pragma unroll
    for (int i = 0; i < 16; i++)
        vt[(size_t)(bh * HD + i * 4 + rr) * TT + s0 + csw] = t[c][i * 4 + rr];
}

// ---- flash attention v3: LDS-staged dbuf K/V, swapped QK^T, in-reg softmax,
//      defer-max, zero-shuffle P->PV. 4 waves x 32 q-rows, KV tile 64. ----
__global__ void __launch_bounds__(256, 2) fattn(const short* __restrict__ q,
                                                const short* __restrict__ k,
                                                const short* __restrict__ vt,
                                                float* __restrict__ out) {
    __shared__ short kbuf[2][4096];   // [64 rows][64 cols(128B)], XOR-swizzled
    __shared__ short vbuf[2][4096];
    const int tid = threadIdx.x, lane = tid & 63, wid = tid >> 6;
    const int l15 = lane & 15, lg = lane >> 4;
    const int q0 = blockIdx.x * 128 + wid * 32;
    const int bh = blockIdx.y, b = bh >> 4, h = bh & 15;

    // Q fragments [qb][dhalf]: B-operand, col=q(l15), k=d(lg*8+j)
    short8 qf[2][2];
    #pragma unroll
    for (int qb = 0; qb < 2; qb++) {
        const short* qp = q + (size_t)(b * TT + q0 + qb * 16 + l15) * NE + h * HD + lg * 8;
        qf[qb][0] = *(const short8*)qp;
        qf[qb][1] = *(const short8*)(qp + 32);
    }

    floatx4 acc_o[2][4];
    float m_run[2] = {-1e30f, -1e30f}, l_run[2] = {0.f, 0.f};
    floatx4 zero = {0.f, 0.f, 0.f, 0.f};
    #pragma unroll
    for (int qb = 0; qb < 2; qb++)
        #pragma unroll
        for (int db = 0; db < 4; db++) acc_o[qb][db] = zero;

    // staging source addresses (pre-swizzled global col per rule 21)
    const char* kgb = (const char*)(k + (size_t)(b * TT) * NE + h * HD);
    const char* vgb = (const char*)(vt + (size_t)bh * HD * TT);
    const int srow = tid >> 3;               // tile row 0..31 (+32 for 2nd instr)
    const int ssw  = ((tid & 7) * 16) ^ ((srow & 7) << 4);
    const char* ksrc = kgb + (size_t)srow * (NE * 2) + ssw;
    const char* vsrc = vgb + (size_t)srow * (TT * 2) + ssw;

    // fragment ds_read lane bases (swizzled)
    const int swz  = (l15 & 7) << 4;
    const int rd0  = l15 * 128 + ((lg * 16) ^ swz);
    const int rd1  = l15 * 128 + ((64 + lg * 16) ^ swz);

#define STAGE(buf, s0v) do { \
    const char* ks_ = ksrc + (size_t)(s0v) * (NE * 2); \
    gload_lds16(ks_,                 &kbuf[buf][wid * 512]); \
    gload_lds16(ks_ + 32 * (NE * 2), &kbuf[buf][wid * 512 + 2048]); \
    const char* vs_ = vsrc + (size_t)(s0v) * 2; \
    gload_lds16(vs_,                 &vbuf[buf][wid * 512]); \
    gload_lds16(vs_ + 32 * (TT * 2), &vbuf[buf][wid * 512 + 2048]); \
} while (0)

    STAGE(0, 0);
    __syncthreads();

    for (int t = 0; t < 32; ++t) {
        const int cur = t & 1;
        if (t < 31) STAGE(cur ^ 1, (t + 1) * 64);

        const char* kb = (const char*)kbuf[cur];
        const char* vb = (const char*)vbuf[cur];

        // K fragments [cb][half]: A-operand, row=k(16cb+l15)
        short8 kf[4][2];
        #pragma unroll
        for (int cb = 0; cb < 4; cb++) {
            kf[cb][0] = *(const short8*)(kb + cb * 2048 + rd0);
            kf[cb][1] = *(const short8*)(kb + cb * 2048 + rd1);
        }
        // swapped QK^T: sacc[qb][cb] = P_log2[s=16cb+4lg+r][q=16qb+l15]
        floatx4 sacc[2][4];
        #pragma unroll
        for (int qb = 0; qb < 2; qb++)
            #pragma unroll
            for (int cb = 0; cb < 4; cb++) sacc[qb][cb] = zero;
        __builtin_amdgcn_s_setprio(1);
        #pragma unroll
        for (int qb = 0; qb < 2; qb++)
            #pragma unroll
            for (int cb = 0; cb < 4; cb++) {
                sacc[qb][cb] = __builtin_amdgcn_mfma_f32_16x16x32_bf16(kf[cb][0], qf[qb][0], sacc[qb][cb], 0, 0, 0);
                sacc[qb][cb] = __builtin_amdgcn_mfma_f32_16x16x32_bf16(kf[cb][1], qf[qb][1], sacc[qb][cb], 0, 0, 0);
            }
        __builtin_amdgcn_s_setprio(0);

        // V fragments [ks][db] (issue ds_reads before softmax to hide latency)
        short8 vf[2][4];
        #pragma unroll
        for (int db = 0; db < 4; db++) {
            vf[0][db] = *(const short8*)(vb + db * 2048 + rd0);
            vf[1][db] = *(const short8*)(vb + db * 2048 + rd1);
        }

        // in-register online softmax with defer-max (THR=8 in log2 units)
        short8 paf[2][2];
        float alpha[2];
        bool slow[2];
        #pragma unroll
        for (int qb = 0; qb < 2; qb++) {
            float p[16];
            #pragma unroll
            for (int cb = 0; cb < 4; cb++)
                #pragma unroll
                for (int r = 0; r < 4; r++) p[cb * 4 + r] = sacc[qb][cb][r];
            float mx = fmaxf(fmaxf(fmaxf(p[0], p[1]), fmaxf(p[2], p[3])),
                             fmaxf(fmaxf(p[4], p[5]), fmaxf(p[6], p[7])));
            float mx2 = fmaxf(fmaxf(fmaxf(p[8], p[9]), fmaxf(p[10], p[11])),
                              fmaxf(fmaxf(p[12], p[13]), fmaxf(p[14], p[15])));
            mx = fmaxf(mx, mx2);
            mx = fmaxf(mx, __shfl_xor(mx, 16));
            mx = fmaxf(mx, __shfl_xor(mx, 32));
            float mn, al;
            slow[qb] = !__all(mx <= m_run[qb] + 8.0f);
            if (slow[qb]) {
                mn = fmaxf(m_run[qb], mx);
                al = exp2f(m_run[qb] - mn);
                m_run[qb] = mn;
            } else { mn = m_run[qb]; al = 1.0f; }
            alpha[qb] = al;
            float rs = 0.f;
            #pragma unroll
            for (int i = 0; i < 16; i++) { p[i] = exp2f(p[i] - mn); rs += p[i]; }
            rs += __shfl_xor(rs, 16);
            rs += __shfl_xor(rs, 32);
            l_run[qb] = slow[qb] ? (l_run[qb] * al + rs) : (l_run[qb] + rs);
            #pragma unroll
            for (int ks = 0; ks < 2; ks++) {
                short8 pa;
                #pragma unroll
                for (int j = 0; j < 8; j++) pa[j] = f2bf_hw(p[ks * 8 + j]);
                paf[qb][ks] = pa;
            }
        }
        // rescale acc_o only when max moved (wave-uniform branch)
        #pragma unroll
        for (int qb = 0; qb < 2; qb++) {
            if (slow[qb]) {
                #pragma unroll
                for (int r = 0; r < 4; r++) {
                    float al = __shfl(alpha[qb], lg * 4 + r);
                    #pragma unroll
                    for (int db = 0; db < 4; db++) acc_o[qb][db][r] *= al;
                }
            }
        }
        // PV
        __builtin_amdgcn_s_setprio(1);
        #pragma unroll
        for (int qb = 0; qb < 2; qb++)
            #pragma unroll
            for (int ks = 0; ks < 2; ks++)
                #pragma unroll
                for (int db = 0; db < 4; db++)
                    acc_o[qb][db] = __builtin_amdgcn_mfma_f32_16x16x32_bf16(paf[qb][ks], vf[ks][db], acc_o[qb][db], 0, 0, 0);
        __builtin_amdgcn_s_setprio(0);
        __syncthreads();
    }
#undef STAGE
    // epilogue: normalize by l (broadcast from QK layout) and store fp32
    #pragma unroll
    for (int qb = 0; qb < 2; qb++) {
        #pragma unroll
        for (int r = 0; r < 4; r++) {
            float li = __shfl(l_run[qb], lg * 4 + r);
            float inv = 1.0f / li;
            #pragma unroll
            for (int db = 0; db < 4; db++)
                out[(size_t)(b * TT + q0 + qb * 16 + lg * 4 + r) * NE + h * HD + db * 16 + l15] =
                    acc_o[qb][db][r] * inv;
        }
    }
}

extern "C" void kernel_launch(void* const* d_in, const int* in_sizes, int n_in,
                              void* d_out, int out_size, void* d_ws, size_t ws_size,
                              hipStream_t stream) {
    const float* x_enc = (const float*)d_in[0];
    const float* x     = (const float*)d_in[1];
    const float* Wk    = (const float*)d_in[2];
    const float* Wq    = (const float*)d_in[3];
    const float* Wv    = (const float*)d_in[4];
    float* out = (float*)d_out;

    const size_t SZ = (size_t)MM * NE;
    short* x_bf    = (short*)d_ws;
    short* xenc_bf = x_bf + SZ;
    short* Wt      = xenc_bf + SZ;
    short* qkv     = Wt + 3 * (size_t)NE * NE;
    short* vt      = qkv + 3 * SZ;

    cvt_bf16<<<dim3(2048), dim3(256), 0, stream>>>(x,     x_bf,    (int)(SZ / 8));
    cvt_bf16<<<dim3(2048), dim3(256), 0, stream>>>(x_enc, xenc_bf, (int)(SZ / 8));
    wtrans<<<dim3(32, 32, 3), dim3(256), 0, stream>>>(Wq, Wk, Wv, Wt);
    gemm_bt<<<dim3(8, 32, 3), dim3(256), 0, stream>>>(x_bf, xenc_bf, Wt, qkv);
    vtrans<<<dim3(32, 32), dim3(256), 0, stream>>>(qkv + 2 * SZ, vt);
    fattn<<<dim3(16, 32), dim3(256), 0, stream>>>(qkv, qkv + SZ, vt, out);
}

// Round 4
// 118.386 us; speedup vs baseline: 2.4877x; 1.1550x over previous
//
#include <hip/hip_runtime.h>
#include <hip/hip_bf16.h>
#include <stdint.h>

#define NE 1024
#define NH 16
#define HD 64
#define BB 2
#define TT 2048
#define MM (BB*TT)

typedef __attribute__((ext_vector_type(8))) short short8;
typedef __attribute__((ext_vector_type(4))) float floatx4;

__device__ __forceinline__ short f2bf(float f) {
    union { float f; uint32_t u; } v; v.f = f;
    uint32_t u = v.u;
    return (short)((u + 0x7fffu + ((u >> 16) & 1u)) >> 16);
}

__device__ __forceinline__ short f2bf_hw(float f) {
    __hip_bfloat16 h = __float2bfloat16(f);
    union { __hip_bfloat16 h; short s; } u; u.h = h;
    return u.s;
}

__device__ __forceinline__ void gload_lds16(const void* g, void* l) {
    __builtin_amdgcn_global_load_lds((__attribute__((address_space(1))) void*)g,
                                     (__attribute__((address_space(3))) void*)l,
                                     16, 0, 0);
}

// ---- fp32 -> bf16 elementwise, 8 elems/thread ----
__global__ void cvt_bf16(const float* __restrict__ in, short* __restrict__ out, int n8) {
    int i = blockIdx.x * blockDim.x + threadIdx.x;
    if (i >= n8) return;
    const floatx4* p = (const floatx4*)(in + (size_t)i * 8);
    floatx4 a = p[0], b = p[1];
    short8 r;
    #pragma unroll
    for (int j = 0; j < 4; j++) { r[j] = f2bf_hw(a[j]); r[4 + j] = f2bf_hw(b[j]); }
    *(short8*)(out + (size_t)i * 8) = r;
}

// ---- W [K,N] fp32 -> Wt [N,K] bf16 (transpose + convert) ----
__global__ void wtrans(const float* __restrict__ Wq, const float* __restrict__ Wk,
                       const float* __restrict__ Wv, short* __restrict__ Wt) {
    __shared__ float t[32][33];
    const float* W = blockIdx.z == 0 ? Wq : (blockIdx.z == 1 ? Wk : Wv);
    short* dst = Wt + (size_t)blockIdx.z * NE * NE;
    int n0 = blockIdx.x * 32, k0 = blockIdx.y * 32;
    int tx = threadIdx.x & 31, ty = threadIdx.x >> 5;
    #pragma unroll
    for (int i = 0; i < 4; i++)
        t[ty * 4 + i][tx] = W[(size_t)(k0 + ty * 4 + i) * NE + n0 + tx];
    __syncthreads();
    #pragma unroll
    for (int i = 0; i < 4; i++)
        dst[(size_t)(n0 + ty * 4 + i) * NE + k0 + tx] = f2bf_hw(t[tx][ty * 4 + i]);
}

// ---- GEMM: C[M,N] bf16 = A[M,K] bf16 @ Bt[N,K]^T ; M=4096, N=K=1024 ----
__global__ void __launch_bounds__(256) gemm_bt(const short* __restrict__ x_bf,
                                               const short* __restrict__ xenc_bf,
                                               const short* __restrict__ Wt,
                                               short* __restrict__ qkv) {
    __shared__ short sA[128 * 32];
    __shared__ short sB[128 * 32];
    const int z = blockIdx.z;
    const short* A  = (z == 0) ? x_bf : xenc_bf;
    const short* Bt = Wt + (size_t)z * NE * NE;
    short* C = qkv + (size_t)z * MM * NE;
    const float osc = (z == 0) ? 0.04508422f : 1.0f;  // (1/32)*log2(e)

    const int tid = threadIdx.x;
    const int lane = tid & 63, wid = tid >> 6;
    const int l15 = lane & 15, lg = lane >> 4;
    const int wr = wid >> 1, wc = wid & 1;
    const int m0 = blockIdx.y * 128, n0 = blockIdx.x * 128;

    const short* gA = A  + (size_t)(m0 + (tid >> 2)) * NE + (tid & 3) * 8;
    const short* gB = Bt + (size_t)(n0 + (tid >> 2)) * NE + (tid & 3) * 8;
    short* lA = sA + wid * 512;
    short* lB = sB + wid * 512;

    floatx4 acc[4][4];
    floatx4 zero = {0.f, 0.f, 0.f, 0.f};
    #pragma unroll
    for (int i = 0; i < 4; i++)
        #pragma unroll
        for (int j = 0; j < 4; j++) acc[i][j] = zero;

    for (int kt = 0; kt < NE; kt += 32) {
        gload_lds16(gA + kt,            lA);
        gload_lds16(gA + 64 * NE + kt,  lA + 2048);
        gload_lds16(gB + kt,            lB);
        gload_lds16(gB + 64 * NE + kt,  lB + 2048);
        __syncthreads();
        short8 af[4], bfr[4];
        #pragma unroll
        for (int i = 0; i < 4; i++) {
            af[i]  = *(const short8*)&sA[(wr * 64 + i * 16 + l15) * 32 + lg * 8];
            bfr[i] = *(const short8*)&sB[(wc * 64 + i * 16 + l15) * 32 + lg * 8];
        }
        #pragma unroll
        for (int i = 0; i < 4; i++)
            #pragma unroll
            for (int j = 0; j < 4; j++)
                acc[i][j] = __builtin_amdgcn_mfma_f32_16x16x32_bf16(af[i], bfr[j], acc[i][j], 0, 0, 0);
        __syncthreads();
    }
    #pragma unroll
    for (int i = 0; i < 4; i++)
        #pragma unroll
        for (int j = 0; j < 4; j++)
            #pragma unroll
            for (int r = 0; r < 4; r++) {
                int row = m0 + wr * 64 + i * 16 + lg * 4 + r;
                int col = n0 + wc * 64 + j * 16 + l15;
                C[(size_t)row * NE + col] = f2bf_hw(acc[i][j][r] * osc);
            }
}

// ---- v [B*T, NE] bf16 -> vt[(bh)*64+d][s'] bf16, s' swizzled within 64-blocks ----
__global__ void vtrans(const short* __restrict__ v, short* __restrict__ vt) {
    __shared__ short t[64][65];
    int s0 = blockIdx.x * 64;
    int bh = blockIdx.y;
    int b = bh >> 4, h = bh & 15;
    int tid = threadIdx.x;
    int c = tid & 63, rr = tid >> 6;
    #pragma unroll
    for (int i = 0; i < 16; i++)
        t[i * 4 + rr][c] = v[(size_t)(b * TT + s0 + i * 4 + rr) * NE + h * HD + c];
    __syncthreads();
    int csw = (c & 35) | (((c >> 4) & 1) << 2) | (((c >> 2) & 3) << 3);
    #pragma unroll
    for (int i = 0; i < 16; i++)
        vt[(size_t)(bh * HD + i * 4 + rr) * TT + s0 + csw] = t[c][i * 4 + rr];
}

// ---- flash attention v4: static-max softmax (shift-exact), 3-buf counted-vmcnt
//      pipeline, swapped QK^T, zero-shuffle P->PV. 4 waves x 32 q-rows. ----
__global__ void __launch_bounds__(256, 2) fattn(const short* __restrict__ q,
                                                const short* __restrict__ k,
                                                const short* __restrict__ vt,
                                                float* __restrict__ out) {
    __shared__ short kbuf[3][4096];
    __shared__ short vbuf[3][4096];
    const int tid = threadIdx.x, lane = tid & 63, wid = tid >> 6;
    const int l15 = lane & 15, lg = lane >> 4;
    const int q0 = blockIdx.x * 128 + wid * 32;
    const int bh = blockIdx.y, b = bh >> 4, h = bh & 15;

    short8 qf[2][2];
    #pragma unroll
    for (int qb = 0; qb < 2; qb++) {
        const short* qp = q + (size_t)(b * TT + q0 + qb * 16 + l15) * NE + h * HD + lg * 8;
        qf[qb][0] = *(const short8*)qp;
        qf[qb][1] = *(const short8*)(qp + 32);
    }

    floatx4 acc_o[2][4];
    float lsum[2] = {0.f, 0.f};
    floatx4 zero = {0.f, 0.f, 0.f, 0.f};
    #pragma unroll
    for (int qb = 0; qb < 2; qb++)
        #pragma unroll
        for (int db = 0; db < 4; db++) acc_o[qb][db] = zero;

    const char* kgb = (const char*)(k + (size_t)(b * TT) * NE + h * HD);
    const char* vgb = (const char*)(vt + (size_t)bh * HD * TT);
    const int srow = tid >> 3;               // 0..31 (+32 via 2nd instr)
    const int ssw  = ((tid & 7) * 16) ^ ((srow & 7) << 4);
    const char* ksrc = kgb + (size_t)srow * (NE * 2) + ssw;
    const char* vsrc = vgb + (size_t)srow * (TT * 2) + ssw;

    const int swz  = (l15 & 7) << 4;
    const int rd0  = l15 * 128 + ((lg * 16) ^ swz);
    const int rd1  = l15 * 128 + ((64 + lg * 16) ^ swz);

#define STAGE(bi, s0v) do { \
    const char* ks_ = ksrc + (size_t)(s0v) * (NE * 2); \
    gload_lds16(ks_,                 &kbuf[bi][wid * 512]); \
    gload_lds16(ks_ + 32 * (NE * 2), &kbuf[bi][wid * 512 + 2048]); \
    const char* vs_ = vsrc + (size_t)(s0v) * 2; \
    gload_lds16(vs_,                 &vbuf[bi][wid * 512]); \
    gload_lds16(vs_ + 32 * (TT * 2), &vbuf[bi][wid * 512 + 2048]); \
} while (0)

#define FATTN_COMPUTE(cur) do { \
    const char* kb = (const char*)kbuf[cur]; \
    const char* vb = (const char*)vbuf[cur]; \
    short8 kf[4][2]; \
    _Pragma("unroll") \
    for (int cb = 0; cb < 4; cb++) { \
        kf[cb][0] = *(const short8*)(kb + cb * 2048 + rd0); \
        kf[cb][1] = *(const short8*)(kb + cb * 2048 + rd1); \
    } \
    floatx4 sacc[2][4]; \
    _Pragma("unroll") \
    for (int qb = 0; qb < 2; qb++) \
        _Pragma("unroll") \
        for (int cb = 0; cb < 4; cb++) sacc[qb][cb] = zero; \
    __builtin_amdgcn_s_setprio(1); \
    _Pragma("unroll") \
    for (int qb = 0; qb < 2; qb++) \
        _Pragma("unroll") \
        for (int cb = 0; cb < 4; cb++) { \
            sacc[qb][cb] = __builtin_amdgcn_mfma_f32_16x16x32_bf16(kf[cb][0], qf[qb][0], sacc[qb][cb], 0, 0, 0); \
            sacc[qb][cb] = __builtin_amdgcn_mfma_f32_16x16x32_bf16(kf[cb][1], qf[qb][1], sacc[qb][cb], 0, 0, 0); \
        } \
    __builtin_amdgcn_s_setprio(0); \
    short8 vf[2][4]; \
    _Pragma("unroll") \
    for (int db = 0; db < 4; db++) { \
        vf[0][db] = *(const short8*)(vb + db * 2048 + rd0); \
        vf[1][db] = *(const short8*)(vb + db * 2048 + rd1); \
    } \
    short8 paf[2][2]; \
    _Pragma("unroll") \
    for (int qb = 0; qb < 2; qb++) { \
        float pe[16]; \
        _Pragma("unroll") \
        for (int cb = 0; cb < 4; cb++) \
            _Pragma("unroll") \
            for (int r = 0; r < 4; r++) \
                pe[cb * 4 + r] = exp2f(sacc[qb][cb][r] - 8.0f); \
        float s0_ = (pe[0] + pe[1]) + (pe[2] + pe[3]); \
        float s1_ = (pe[4] + pe[5]) + (pe[6] + pe[7]); \
        float s2_ = (pe[8] + pe[9]) + (pe[10] + pe[11]); \
        float s3_ = (pe[12] + pe[13]) + (pe[14] + pe[15]); \
        lsum[qb] += (s0_ + s1_) + (s2_ + s3_); \
        _Pragma("unroll") \
        for (int ks = 0; ks < 2; ks++) { \
            short8 pa; \
            _Pragma("unroll") \
            for (int j = 0; j < 8; j++) pa[j] = f2bf_hw(pe[ks * 8 + j]); \
            paf[qb][ks] = pa; \
        } \
    } \
    __builtin_amdgcn_s_setprio(1); \
    _Pragma("unroll") \
    for (int qb = 0; qb < 2; qb++) \
        _Pragma("unroll") \
        for (int ks = 0; ks < 2; ks++) \
            _Pragma("unroll") \
            for (int db = 0; db < 4; db++) \
                acc_o[qb][db] = __builtin_amdgcn_mfma_f32_16x16x32_bf16(paf[qb][ks], vf[ks][db], acc_o[qb][db], 0, 0, 0); \
    __builtin_amdgcn_s_setprio(0); \
} while (0)

    STAGE(0, 0);
    STAGE(1, 64);
    // 2-deep prefetch: at iter-t entry 8 loads outstanding (t:4, t+1:4);
    // vmcnt(4) retires tile-t's; barrier publishes them; STAGE(t+2) then
    // overwrites buf (t-1)%3, which every wave finished reading before this
    // barrier (compute(t-1) precedes it in program order).
    for (int t = 0; t < 31; ++t) {
        asm volatile("s_waitcnt vmcnt(4)" ::: "memory");
        __builtin_amdgcn_sched_barrier(0);
        __builtin_amdgcn_s_barrier();
        __builtin_amdgcn_sched_barrier(0);
        if (t < 30) STAGE((t + 2) % 3, (t + 2) * 64);
        FATTN_COMPUTE(t % 3);
    }
    asm volatile("s_waitcnt vmcnt(0)" ::: "memory");
    __builtin_amdgcn_sched_barrier(0);
    __builtin_amdgcn_s_barrier();
    __builtin_amdgcn_sched_barrier(0);
    FATTN_COMPUTE(1);   // t = 31, 31 % 3 == 1
#undef STAGE
#undef FATTN_COMPUTE

    // epilogue: reduce l across lg-groups, normalize, store fp32
    #pragma unroll
    for (int qb = 0; qb < 2; qb++) {
        float rs = lsum[qb];
        rs += __shfl_xor(rs, 16);
        rs += __shfl_xor(rs, 32);
        #pragma unroll
        for (int r = 0; r < 4; r++) {
            float li = __shfl(rs, lg * 4 + r);
            float inv = 1.0f / li;
            #pragma unroll
            for (int db = 0; db < 4; db++)
                out[(size_t)(b * TT + q0 + qb * 16 + lg * 4 + r) * NE + h * HD + db * 16 + l15] =
                    acc_o[qb][db][r] * inv;
        }
    }
}

extern "C" void kernel_launch(void* const* d_in, const int* in_sizes, int n_in,
                              void* d_out, int out_size, void* d_ws, size_t ws_size,
                              hipStream_t stream) {
    const float* x_enc = (const float*)d_in[0];
    const float* x     = (const float*)d_in[1];
    const float* Wk    = (const float*)d_in[2];
    const float* Wq    = (const float*)d_in[3];
    const float* Wv    = (const float*)d_in[4];
    float* out = (float*)d_out;

    const size_t SZ = (size_t)MM * NE;
    short* x_bf    = (short*)d_ws;
    short* xenc_bf = x_bf + SZ;
    short* Wt      = xenc_bf + SZ;
    short* qkv     = Wt + 3 * (size_t)NE * NE;
    short* vt      = qkv + 3 * SZ;

    cvt_bf16<<<dim3(2048), dim3(256), 0, stream>>>(x,     x_bf,    (int)(SZ / 8));
    cvt_bf16<<<dim3(2048), dim3(256), 0, stream>>>(x_enc, xenc_bf, (int)(SZ / 8));
    wtrans<<<dim3(32, 32, 3), dim3(256), 0, stream>>>(Wq, Wk, Wv, Wt);
    gemm_bt<<<dim3(8, 32, 3), dim3(256), 0, stream>>>(x_bf, xenc_bf, Wt, qkv);
    vtrans<<<dim3(32, 32), dim3(256), 0, stream>>>(qkv + 2 * SZ, vt);
    fattn<<<dim3(16, 32), dim3(256), 0, stream>>>(qkv, qkv + SZ, vt, out);
}

// Round 5
// 101.585 us; speedup vs baseline: 2.8991x; 1.1654x over previous
//
#include <hip/hip_runtime.h>
#include <hip/hip_bf16.h>
#include <stdint.h>

#define NE 1024
#define NH 16
#define HD 64
#define BB 2
#define TT 2048
#define MM (BB*TT)

typedef __attribute__((ext_vector_type(8))) short short8;
typedef __attribute__((ext_vector_type(4))) float floatx4;

__device__ __forceinline__ short f2bf(float f) {
    union { float f; uint32_t u; } v; v.f = f;
    uint32_t u = v.u;
    return (short)((u + 0x7fffu + ((u >> 16) & 1u)) >> 16);
}

__device__ __forceinline__ float fast_exp2(float x) {
#if __has_builtin(__builtin_amdgcn_exp2f)
    return __builtin_amdgcn_exp2f(x);
#else
    float r; asm("v_exp_f32 %0, %1" : "=v"(r) : "v"(x)); return r;
#endif
}

__device__ __forceinline__ void gload_lds16(const void* g, void* l) {
    __builtin_amdgcn_global_load_lds((__attribute__((address_space(1))) void*)g,
                                     (__attribute__((address_space(3))) void*)l,
                                     16, 0, 0);
}

// ---- fp32 -> bf16 elementwise, 8 elems/thread, hw packed converts ----
__global__ void cvt_bf16(const float* __restrict__ in, short* __restrict__ out, int n8) {
    int i = blockIdx.x * blockDim.x + threadIdx.x;
    if (i >= n8) return;
    const floatx4* p = (const floatx4*)(in + (size_t)i * 8);
    floatx4 a = p[0], b = p[1];
    union { uint32_t u[4]; short8 s; } r;
    asm("v_cvt_pk_bf16_f32 %0, %1, %2" : "=v"(r.u[0]) : "v"(a[0]), "v"(a[1]));
    asm("v_cvt_pk_bf16_f32 %0, %1, %2" : "=v"(r.u[1]) : "v"(a[2]), "v"(a[3]));
    asm("v_cvt_pk_bf16_f32 %0, %1, %2" : "=v"(r.u[2]) : "v"(b[0]), "v"(b[1]));
    asm("v_cvt_pk_bf16_f32 %0, %1, %2" : "=v"(r.u[3]) : "v"(b[2]), "v"(b[3]));
    *(short8*)(out + (size_t)i * 8) = r.s;
}

// ---- W [K,N] fp32 -> Wt [N,K] bf16 (transpose + convert) ----
__global__ void wtrans(const float* __restrict__ Wq, const float* __restrict__ Wk,
                       const float* __restrict__ Wv, short* __restrict__ Wt) {
    __shared__ float t[32][33];
    const float* W = blockIdx.z == 0 ? Wq : (blockIdx.z == 1 ? Wk : Wv);
    short* dst = Wt + (size_t)blockIdx.z * NE * NE;
    int n0 = blockIdx.x * 32, k0 = blockIdx.y * 32;
    int tx = threadIdx.x & 31, ty = threadIdx.x >> 5;
    #pragma unroll
    for (int i = 0; i < 4; i++)
        t[ty * 4 + i][tx] = W[(size_t)(k0 + ty * 4 + i) * NE + n0 + tx];
    __syncthreads();
    #pragma unroll
    for (int i = 0; i < 4; i++)
        dst[(size_t)(n0 + ty * 4 + i) * NE + k0 + tx] = f2bf(t[tx][ty * 4 + i]);
}

// ---- GEMM: C[M,N] bf16 = A[M,K] bf16 @ Bt[N,K]^T ; M=4096, N=K=1024 ----
__global__ void __launch_bounds__(256) gemm_bt(const short* __restrict__ x_bf,
                                               const short* __restrict__ xenc_bf,
                                               const short* __restrict__ Wt,
                                               short* __restrict__ qkv) {
    __shared__ short sA[128 * 32];
    __shared__ short sB[128 * 32];
    const int z = blockIdx.z;
    const short* A  = (z == 0) ? x_bf : xenc_bf;
    const short* Bt = Wt + (size_t)z * NE * NE;
    short* C = qkv + (size_t)z * MM * NE;
    const float osc = (z == 0) ? 0.04508422f : 1.0f;  // (1/32)*log2(e)

    const int tid = threadIdx.x;
    const int lane = tid & 63, wid = tid >> 6;
    const int l15 = lane & 15, lg = lane >> 4;
    const int wr = wid >> 1, wc = wid & 1;
    const int m0 = blockIdx.y * 128, n0 = blockIdx.x * 128;

    const short* gA = A  + (size_t)(m0 + (tid >> 2)) * NE + (tid & 3) * 8;
    const short* gB = Bt + (size_t)(n0 + (tid >> 2)) * NE + (tid & 3) * 8;
    short* lA = sA + wid * 512;
    short* lB = sB + wid * 512;

    floatx4 acc[4][4];
    floatx4 zero = {0.f, 0.f, 0.f, 0.f};
    #pragma unroll
    for (int i = 0; i < 4; i++)
        #pragma unroll
        for (int j = 0; j < 4; j++) acc[i][j] = zero;

    for (int kt = 0; kt < NE; kt += 32) {
        gload_lds16(gA + kt,            lA);
        gload_lds16(gA + 64 * NE + kt,  lA + 2048);
        gload_lds16(gB + kt,            lB);
        gload_lds16(gB + 64 * NE + kt,  lB + 2048);
        __syncthreads();
        short8 af[4], bfr[4];
        #pragma unroll
        for (int i = 0; i < 4; i++) {
            af[i]  = *(const short8*)&sA[(wr * 64 + i * 16 + l15) * 32 + lg * 8];
            bfr[i] = *(const short8*)&sB[(wc * 64 + i * 16 + l15) * 32 + lg * 8];
        }
        #pragma unroll
        for (int i = 0; i < 4; i++)
            #pragma unroll
            for (int j = 0; j < 4; j++)
                acc[i][j] = __builtin_amdgcn_mfma_f32_16x16x32_bf16(af[i], bfr[j], acc[i][j], 0, 0, 0);
        __syncthreads();
    }
    #pragma unroll
    for (int i = 0; i < 4; i++)
        #pragma unroll
        for (int j = 0; j < 4; j++)
            #pragma unroll
            for (int r = 0; r < 4; r++) {
                int row = m0 + wr * 64 + i * 16 + lg * 4 + r;
                int col = n0 + wc * 64 + j * 16 + l15;
                C[(size_t)row * NE + col] = f2bf(acc[i][j][r] * osc);
            }
}

// ---- v [B*T, NE] bf16 -> vt[(bh)*64+d][s'] bf16, s' swizzled within 64-blocks ----
__global__ void vtrans(const short* __restrict__ v, short* __restrict__ vt) {
    __shared__ short t[64][65];
    int s0 = blockIdx.x * 64;
    int bh = blockIdx.y;
    int b = bh >> 4, h = bh & 15;
    int tid = threadIdx.x;
    int c = tid & 63, rr = tid >> 6;
    #pragma unroll
    for (int i = 0; i < 16; i++)
        t[i * 4 + rr][c] = v[(size_t)(b * TT + s0 + i * 4 + rr) * NE + h * HD + c];
    __syncthreads();
    int csw = (c & 35) | (((c >> 4) & 1) << 2) | (((c >> 2) & 3) << 3);
    #pragma unroll
    for (int i = 0; i < 16; i++)
        vt[(size_t)(bh * HD + i * 4 + rr) * TT + s0 + csw] = t[c][i * 4 + rr];
}

// ---- flash attention v5: static-max softmax baked into MFMA C-init, raw
//      v_exp/v_cvt_pk, ones-MFMA l-accumulation, 3-buf counted-vmcnt pipe. ----
__global__ void __launch_bounds__(256, 2) fattn(const short* __restrict__ q,
                                                const short* __restrict__ k,
                                                const short* __restrict__ vt,
                                                float* __restrict__ out) {
    __shared__ short kbuf[3][4096];
    __shared__ short vbuf[3][4096];
    const int tid = threadIdx.x, lane = tid & 63, wid = tid >> 6;
    const int l15 = lane & 15, lg = lane >> 4;
    const int q0 = blockIdx.x * 128 + wid * 32;
    const int bh = blockIdx.y, b = bh >> 4, h = bh & 15;

    short8 qf[2][2];
    #pragma unroll
    for (int qb = 0; qb < 2; qb++) {
        const short* qp = q + (size_t)(b * TT + q0 + qb * 16 + l15) * NE + h * HD + lg * 8;
        qf[qb][0] = *(const short8*)qp;
        qf[qb][1] = *(const short8*)(qp + 32);
    }
    short8 ones;
    #pragma unroll
    for (int j = 0; j < 8; j++) ones[j] = (short)0x3F80;  // bf16 1.0

    floatx4 acc_o[2][4];
    floatx4 acc_l[2];
    floatx4 zero = {0.f, 0.f, 0.f, 0.f};
    floatx4 minus8 = {-8.f, -8.f, -8.f, -8.f};
    #pragma unroll
    for (int qb = 0; qb < 2; qb++) {
        acc_l[qb] = zero;
        #pragma unroll
        for (int db = 0; db < 4; db++) acc_o[qb][db] = zero;
    }

    const char* kgb = (const char*)(k + (size_t)(b * TT) * NE + h * HD);
    const char* vgb = (const char*)(vt + (size_t)bh * HD * TT);
    const int srow = tid >> 3;               // 0..31 (+32 via 2nd instr)
    const int ssw  = ((tid & 7) * 16) ^ ((srow & 7) << 4);
    const char* ksrc = kgb + (size_t)srow * (NE * 2) + ssw;
    const char* vsrc = vgb + (size_t)srow * (TT * 2) + ssw;

    const int swz  = (l15 & 7) << 4;
    const int rd0  = l15 * 128 + ((lg * 16) ^ swz);
    const int rd1  = l15 * 128 + ((64 + lg * 16) ^ swz);

#define STAGE(bi, s0v) do { \
    const char* ks_ = ksrc + (size_t)(s0v) * (NE * 2); \
    gload_lds16(ks_,                 &kbuf[bi][wid * 512]); \
    gload_lds16(ks_ + 32 * (NE * 2), &kbuf[bi][wid * 512 + 2048]); \
    const char* vs_ = vsrc + (size_t)(s0v) * 2; \
    gload_lds16(vs_,                 &vbuf[bi][wid * 512]); \
    gload_lds16(vs_ + 32 * (TT * 2), &vbuf[bi][wid * 512 + 2048]); \
} while (0)

#define FATTN_COMPUTE(cur) do { \
    const char* kb = (const char*)kbuf[cur]; \
    const char* vb = (const char*)vbuf[cur]; \
    short8 kf[4][2]; \
    _Pragma("unroll") \
    for (int cb = 0; cb < 4; cb++) { \
        kf[cb][0] = *(const short8*)(kb + cb * 2048 + rd0); \
        kf[cb][1] = *(const short8*)(kb + cb * 2048 + rd1); \
    } \
    floatx4 sacc[2][4]; \
    _Pragma("unroll") \
    for (int qb = 0; qb < 2; qb++) \
        _Pragma("unroll") \
        for (int cb = 0; cb < 4; cb++) sacc[qb][cb] = minus8; \
    __builtin_amdgcn_s_setprio(1); \
    _Pragma("unroll") \
    for (int qb = 0; qb < 2; qb++) \
        _Pragma("unroll") \
        for (int cb = 0; cb < 4; cb++) { \
            sacc[qb][cb] = __builtin_amdgcn_mfma_f32_16x16x32_bf16(kf[cb][0], qf[qb][0], sacc[qb][cb], 0, 0, 0); \
            sacc[qb][cb] = __builtin_amdgcn_mfma_f32_16x16x32_bf16(kf[cb][1], qf[qb][1], sacc[qb][cb], 0, 0, 0); \
        } \
    __builtin_amdgcn_s_setprio(0); \
    short8 vf[2][4]; \
    _Pragma("unroll") \
    for (int db = 0; db < 4; db++) { \
        vf[0][db] = *(const short8*)(vb + db * 2048 + rd0); \
        vf[1][db] = *(const short8*)(vb + db * 2048 + rd1); \
    } \
    short8 paf[2][2]; \
    _Pragma("unroll") \
    for (int qb = 0; qb < 2; qb++) { \
        float pe[16]; \
        _Pragma("unroll") \
        for (int cb = 0; cb < 4; cb++) \
            _Pragma("unroll") \
            for (int r = 0; r < 4; r++) \
                pe[cb * 4 + r] = fast_exp2(sacc[qb][cb][r]); \
        _Pragma("unroll") \
        for (int ks = 0; ks < 2; ks++) { \
            union { uint32_t u[4]; short8 s; } pk_; \
            _Pragma("unroll") \
            for (int j2 = 0; j2 < 4; j2++) \
                asm("v_cvt_pk_bf16_f32 %0, %1, %2" \
                    : "=v"(pk_.u[j2]) \
                    : "v"(pe[ks * 8 + 2 * j2]), "v"(pe[ks * 8 + 2 * j2 + 1])); \
            paf[qb][ks] = pk_.s; \
        } \
    } \
    __builtin_amdgcn_s_setprio(1); \
    _Pragma("unroll") \
    for (int qb = 0; qb < 2; qb++) \
        _Pragma("unroll") \
        for (int ks = 0; ks < 2; ks++) { \
            _Pragma("unroll") \
            for (int db = 0; db < 4; db++) \
                acc_o[qb][db] = __builtin_amdgcn_mfma_f32_16x16x32_bf16(paf[qb][ks], vf[ks][db], acc_o[qb][db], 0, 0, 0); \
            acc_l[qb] = __builtin_amdgcn_mfma_f32_16x16x32_bf16(paf[qb][ks], ones, acc_l[qb], 0, 0, 0); \
        } \
    __builtin_amdgcn_s_setprio(0); \
} while (0)

    STAGE(0, 0);
    STAGE(1, 64);
    // 2-deep prefetch: vmcnt(4) retires tile-t's 4 loads; barrier publishes;
    // STAGE(t+2) overwrites buf (t-1)%3 which all waves finished before this
    // barrier (compute(t-1) precedes it in program order).
    for (int t = 0; t < 31; ++t) {
        asm volatile("s_waitcnt vmcnt(4)" ::: "memory");
        __builtin_amdgcn_sched_barrier(0);
        __builtin_amdgcn_s_barrier();
        __builtin_amdgcn_sched_barrier(0);
        if (t < 30) STAGE((t + 2) % 3, (t + 2) * 64);
        FATTN_COMPUTE(t % 3);
    }
    asm volatile("s_waitcnt vmcnt(0)" ::: "memory");
    __builtin_amdgcn_sched_barrier(0);
    __builtin_amdgcn_s_barrier();
    __builtin_amdgcn_sched_barrier(0);
    FATTN_COMPUTE(1);   // t = 31, 31 % 3 == 1
#undef STAGE
#undef FATTN_COMPUTE

    // epilogue: acc_l[qb][r] = l for q-row 4lg+r (all lanes) — no shuffles
    #pragma unroll
    for (int qb = 0; qb < 2; qb++) {
        #pragma unroll
        for (int r = 0; r < 4; r++) {
            float inv = 1.0f / acc_l[qb][r];
            #pragma unroll
            for (int db = 0; db < 4; db++)
                out[(size_t)(b * TT + q0 + qb * 16 + lg * 4 + r) * NE + h * HD + db * 16 + l15] =
                    acc_o[qb][db][r] * inv;
        }
    }
}

extern "C" void kernel_launch(void* const* d_in, const int* in_sizes, int n_in,
                              void* d_out, int out_size, void* d_ws, size_t ws_size,
                              hipStream_t stream) {
    const float* x_enc = (const float*)d_in[0];
    const float* x     = (const float*)d_in[1];
    const float* Wk    = (const float*)d_in[2];
    const float* Wq    = (const float*)d_in[3];
    const float* Wv    = (const float*)d_in[4];
    float* out = (float*)d_out;

    const size_t SZ = (size_t)MM * NE;
    short* x_bf    = (short*)d_ws;
    short* xenc_bf = x_bf + SZ;
    short* Wt      = xenc_bf + SZ;
    short* qkv     = Wt + 3 * (size_t)NE * NE;
    short* vt      = qkv + 3 * SZ;

    cvt_bf16<<<dim3(2048), dim3(256), 0, stream>>>(x,     x_bf,    (int)(SZ / 8));
    cvt_bf16<<<dim3(2048), dim3(256), 0, stream>>>(x_enc, xenc_bf, (int)(SZ / 8));
    wtrans<<<dim3(32, 32, 3), dim3(256), 0, stream>>>(Wq, Wk, Wv, Wt);
    gemm_bt<<<dim3(8, 32, 3), dim3(256), 0, stream>>>(x_bf, xenc_bf, Wt, qkv);
    vtrans<<<dim3(32, 32), dim3(256), 0, stream>>>(qkv + 2 * SZ, vt);
    fattn<<<dim3(16, 32), dim3(256), 0, stream>>>(qkv, qkv + SZ, vt, out);
}